// Round 4
// baseline (229.410 us; speedup 1.0000x reference)
//
#include <hip/hip_runtime.h>
#include <math.h>

// Problem constants: B=2, V=10000, N=16, CIN=128, COUT=64
#define V_CNT 10000
#define NB 16
#define TQ 16          // queries per block in fold_kernel
#define BQ_TOTAL 20000 // B*V
#define NCOL 100000    // B*V*5 output columns for the final GEMM

// ws float layout:
//   [0, 2880)      W45[d][kj]       (64 x 45)
//   [2880, 2925)   Wdir9[kj]        (45)
//   [2944, 3004)   FN[f*3+axis]     (20 x 3 face normals)
//   [4096, 5056)   WdP[r][k*5+c]    (20 x 48, permuted dir-weights, pad 45->48)
//   [8192, ...)    psg[kj][col]     (48 x 100000, TRANSPOSED: kj-major)
#define WS_W45   0
#define WS_WD9   2880
#define WS_FN    2944
#define WS_WDP   4096
#define WS_PSG   8192

__device__ __constant__ int FTC_d[20][5] = {
  {1,4,0,2,3},{2,0,1,4,3},{3,1,0,4,2},{4,2,0,3,1},{0,3,1,2,4},
  {3,2,0,4,1},{4,3,0,2,1},{0,4,1,2,3},{1,0,2,4,3},{2,1,0,4,3},
  {4,0,1,3,2},{0,1,2,3,4},{1,2,0,3,4},{2,3,0,1,4},{3,4,0,1,2},
  {1,3,0,2,4},{0,2,1,3,4},{4,1,0,3,2},{3,0,1,4,2},{2,4,0,1,3}};

// color of face f = _FTC[f][0]
constexpr int COLF[20] = {1,2,3,4,0,3,4,0,1,2,4,0,1,2,3,1,0,4,3,2};

// w9[k][j] = w19[W9MAP[k][j]]
constexpr int W9MAP[9][5] = {
  {0,1,2,2,2},{3,4,5,5,5},
  {9,10,11,12,13},{9,10,12,13,11},{9,10,13,11,12},
  {14,15,16,17,18},{14,15,17,18,16},{14,15,18,16,17},
  {6,7,8,8,8}};

__device__ __constant__ int FACES_d[20][3] = {
  {1,2,7},{1,3,7},{1,3,5},{1,4,5},{1,2,4},{2,7,8},{3,7,9},{3,5,11},{4,5,6},{2,4,10},
  {2,8,10},{7,8,9},{3,9,11},{5,6,11},{4,6,10},{0,8,10},{0,6,10},{0,6,11},{0,9,11},{0,8,9}};

#define PHI_F 1.61803398874989484820f
__device__ __constant__ float VS_d[12][3] = {
  {-1.f,PHI_F,0.f},{1.f,PHI_F,0.f},{-1.f,-PHI_F,0.f},{1.f,-PHI_F,0.f},
  {0.f,-1.f,PHI_F},{0.f,1.f,PHI_F},{0.f,-1.f,-PHI_F},{0.f,1.f,-PHI_F},
  {PHI_F,0.f,-1.f},{PHI_F,0.f,1.f},{-PHI_F,0.f,-1.f},{-PHI_F,0.f,1.f}};

__device__ __forceinline__ float fast_tanh(float x){
  float e = __expf(2.0f * x);
  return 1.0f - 2.0f * __builtin_amdgcn_rcpf(e + 1.0f);
}

#define FOR9(M) M(0) M(1) M(2) M(3) M(4) M(5) M(6) M(7) M(8)

// de5s layout: [ql][n*8 + c] with ql-stride 132 floats (16B-aligned, banks shift 4/ql)
#define DE5_STRIDE 132

// ---------------------------------------------------------------------------
// Kernel 1: weight prep. Blocks 0..63: W45[d]. Block 64: Wdir9, face normals,
//           and the permuted dir-weight table WdP[r][k*5+c] = wd9[k][jinv_r(c)].
// ---------------------------------------------------------------------------
__global__ __launch_bounds__(128) void prep_kernel(const float* __restrict__ W,
                                                   const float* __restrict__ Wdir,
                                                   float* __restrict__ ws){
  __shared__ float buf[128][20];
  __shared__ float w19s[19];
  int d = blockIdx.x;   // 0..64
  int c = threadIdx.x;  // 0..127

  const float* src = (d < 64) ? (W + ((size_t)d*128 + c)*19) : (Wdir + (size_t)c*19);
  #pragma unroll
  for (int tt = 0; tt < 19; ++tt) buf[c][tt] = src[tt];

  if (d == 64 && c < 20){
    float x=0.f, y=0.f, z=0.f;
    #pragma unroll
    for (int vv=0; vv<3; ++vv){
      int vi = FACES_d[c][vv];
      x += VS_d[vi][0]; y += VS_d[vi][1]; z += VS_d[vi][2];
    }
    float inv = rsqrtf(x*x + y*y + z*z);
    ws[WS_FN + c*3 + 0] = x*inv;
    ws[WS_FN + c*3 + 1] = y*inv;
    ws[WS_FN + c*3 + 2] = z*inv;
  }
  __syncthreads();

  if (c < 19){
    float s = 0.f;
    for (int i = 0; i < 128; ++i) s += buf[i][c];
    w19s[c] = s;
  }
  __syncthreads();

  if (c < 45){
    int k = c / 5, j = c % 5;
    float v = w19s[W9MAP[k][j]];
    ws[(d < 64) ? (WS_W45 + d*45 + c) : (WS_WD9 + c)] = v;
  }
  if (d == 64){
    // WdP[r][k*5+c] = wd9[k][jinv] where FTC[r][jinv] == c
    for (int i = c; i < 20*45; i += 128){
      int r  = i / 45;
      int kc = i - r*45;
      int k  = kc / 5, cc = kc - k*5;
      int jinv = 0;
      #pragma unroll
      for (int j = 0; j < 5; ++j) if (FTC_d[r][j] == cc) jinv = j;
      ws[WS_WDP + r*48 + kc] = w19s[W9MAP[k][jinv]];
    }
  }
}

// ---------------------------------------------------------------------------
// Kernel 2: fold, COLOR-SPACE inner loop.
//  Round-3 evidence: permuted per-element LDS gathers (5 indexed ds_read_b32
//  per n) let the compiler rematerialize LDS reads to hold VGPRs at 44 ->
//  ~700 serialized ~120cyc LDS round-trips/thread -> 137us, VALUBusy 14%.
//  Now: per n ONE ds_read_b128 + ONE ds_read_b32 (contiguous color vector);
//  the permutation lives in pre-permuted weights WdP[r] (global, loop-
//  invariant, named scalars) and in the final atomic target index.
// ---------------------------------------------------------------------------
__global__ __launch_bounds__(320, 2) void fold_kernel(const int*   __restrict__ nbr,
                                                      const float* __restrict__ verts,
                                                      const float* __restrict__ ws,
                                                      float* __restrict__ psg){
  __shared__ float de5s[TQ*DE5_STRIDE];   // 8448 B
  __shared__ float Ps2[TQ][5][49];        // 15680 B
  int t = threadIdx.x;
  int blockq0 = blockIdx.x * TQ;

  float* psf = &Ps2[0][0][0];
  for (int i = t; i < TQ*5*49; i += 320) psf[i] = 0.f;
  __syncthreads();

  if (t < TQ*NB){
    int ql = t >> 4;
    int n  = t & 15;
    int qg = blockq0 + ql;
    int q  = (qg >= V_CNT) ? (qg - V_CNT) : qg;
    int b0 = qg - q;
    int idx = nbr[qg*NB + n];
    float vx = verts[qg*3+0], vy = verts[qg*3+1], vz = verts[qg*3+2];
    const float* nv = verts + (size_t)(b0 + idx)*3;
    float dx = nv[0]-vx, dy = nv[1]-vy, dz = nv[2]-vz;
    float dd = dx*dx + dy*dy + dz*dz;
    float inv = (dd > 0.f) ? rsqrtf(dd) : 0.f;
    dx *= inv; dy *= inv; dz *= inv;
    const float* fnp = ws + WS_FN;
    float s0=0.f, s1=0.f, s2=0.f, s3=0.f, s4=0.f;
    #pragma unroll
    for (int f = 0; f < 20; ++f){
      float x = fnp[f*3+0]*dx + fnp[f*3+1]*dy + fnp[f*3+2]*dz;
      float th = fast_tanh(x);
      if      (COLF[f]==0) s0 += th;
      else if (COLF[f]==1) s1 += th;
      else if (COLF[f]==2) s2 += th;
      else if (COLF[f]==3) s3 += th;
      else                 s4 += th;
    }
    float* dp = &de5s[ql*DE5_STRIDE + n*8];
    dp[0]=s0; dp[1]=s1; dp[2]=s2; dp[3]=s3; dp[4]=s4;
  }
  __syncthreads();

  {
    int ql = t / 20;
    int r  = t - ql*20;
    int sr = FTC_d[r][0];                          // color(r)
    // jinv[c]: position of color c in FTC[r]
    int ji0=0, ji1=0, ji2=0, ji3=0, ji4=0;
    #pragma unroll
    for (int j = 0; j < 5; ++j){
      int f = FTC_d[r][j];
      if (f==0) ji0=j; else if (f==1) ji1=j; else if (f==2) ji2=j;
      else if (f==3) ji3=j; else ji4=j;
    }

    const float* wp = ws + WS_WDP + r*48;          // per-thread (r-dep), contiguous
#define DECL_P(K) const float p##K##0=wp[K*5+0], p##K##1=wp[K*5+1], \
    p##K##2=wp[K*5+2], p##K##3=wp[K*5+3], p##K##4=wp[K*5+4];
    FOR9(DECL_P)
#undef DECL_P
#define DECL_A(K) float aC##K##0=0.f, aC##K##1=0.f, aC##K##2=0.f, \
    aC##K##3=0.f, aC##K##4=0.f;
    FOR9(DECL_A)
#undef DECL_A

    const float* dql = &de5s[ql*DE5_STRIDE];
    for (int n = 0; n < NB; ++n){
      float4 ev = *(const float4*)(dql + n*8);     // ds_read_b128: colors 0..3
      float  e4 = dql[n*8 + 4];                    // ds_read_b32:  color 4
      float e0 = ev.x, e1 = ev.y, e2 = ev.z, e3 = ev.w;
#define KSTEP(K) { \
      float a = fmaxf(p##K##0*e0 + p##K##1*e1 + p##K##2*e2 \
                    + p##K##3*e3 + p##K##4*e4, 0.f); \
      aC##K##0 = fmaf(a, e0, aC##K##0); \
      aC##K##1 = fmaf(a, e1, aC##K##1); \
      aC##K##2 = fmaf(a, e2, aC##K##2); \
      aC##K##3 = fmaf(a, e3, aC##K##3); \
      aC##K##4 = fmaf(a, e4, aC##K##4); }
      FOR9(KSTEP)
#undef KSTEP
    }

    // P_r[k][j] = accC[k][FTC[r][j]]  =>  Ps[sr][k*5 + jinv[c]] += accC[k][c]
    float* base = &Ps2[ql][sr][0];
#define KAT(K) atomicAdd(base + K*5 + ji0, aC##K##0); \
               atomicAdd(base + K*5 + ji1, aC##K##1); \
               atomicAdd(base + K*5 + ji2, aC##K##2); \
               atomicAdd(base + K*5 + ji3, aC##K##3); \
               atomicAdd(base + K*5 + ji4, aC##K##4);
    FOR9(KAT)
#undef KAT
  }
  __syncthreads();

  // transposed store: psg[kj][col], col = qg*5+s. 45*80 = 3600 elements.
  for (int i = t; i < 45*80; i += 320){
    int kj = i / 80;
    int qs = i - kj*80;                            // ql*5 + s
    psg[(size_t)kj*NCOL + blockq0*5 + qs] = Ps2[qs/5][qs%5][kj];
  }
}

// ---------------------------------------------------------------------------
// Kernel 3: out[b,d,q,s] = sum_kj W45[d][kj] * psg[kj][c],  c = qg*5+s.
//  psg kj-major -> all 45 B-loads coalesced. breg as named scalars.
// ---------------------------------------------------------------------------
__global__ __launch_bounds__(256, 2) void out_kernel(const float* __restrict__ ws,
                                                     const float* __restrict__ psg,
                                                     float* __restrict__ out){
  int c = blockIdx.x*256 + threadIdx.x;
  if (c >= NCOL) return;
#define DECL_B(K) const float bb##K##0=psg[(size_t)(K*5+0)*NCOL + c], \
    bb##K##1=psg[(size_t)(K*5+1)*NCOL + c], bb##K##2=psg[(size_t)(K*5+2)*NCOL + c], \
    bb##K##3=psg[(size_t)(K*5+3)*NCOL + c], bb##K##4=psg[(size_t)(K*5+4)*NCOL + c];
  FOR9(DECL_B)
#undef DECL_B

  int bt = (c >= 50000) ? 1 : 0;
  int local = c - bt*50000;                        // q*5 + s
  float* ob = out + (size_t)bt*3200000 + local;

  for (int d = 0; d < 64; ++d){
    const float* wrow = ws + WS_W45 + d*45;        // wave-uniform -> s_loads
    float a0=0.f, a1=0.f, a2=0.f, a3=0.f, a4=0.f;
#define BD(K) a0 = fmaf(wrow[K*5+0], bb##K##0, a0); \
              a1 = fmaf(wrow[K*5+1], bb##K##1, a1); \
              a2 = fmaf(wrow[K*5+2], bb##K##2, a2); \
              a3 = fmaf(wrow[K*5+3], bb##K##3, a3); \
              a4 = fmaf(wrow[K*5+4], bb##K##4, a4);
    FOR9(BD)
#undef BD
    ob[(size_t)d*50000] = ((a0+a1)+(a2+a3))+a4;
  }
}

extern "C" void kernel_launch(void* const* d_in, const int* in_sizes, int n_in,
                              void* d_out, int out_size, void* d_ws, size_t ws_size,
                              hipStream_t stream){
  const int*   nbr   = (const int*)d_in[0];
  const float* verts = (const float*)d_in[1];
  const float* W     = (const float*)d_in[2];
  const float* Wdir  = (const float*)d_in[3];
  float* out = (float*)d_out;
  float* ws  = (float*)d_ws;           // needs ~19.3 MB scratch
  float* psg = ws + WS_PSG;

  hipLaunchKernelGGL(prep_kernel, dim3(65), dim3(128), 0, stream, W, Wdir, ws);
  hipLaunchKernelGGL(fold_kernel, dim3(BQ_TOTAL/TQ), dim3(320), 0, stream, nbr, verts, ws, psg);
  hipLaunchKernelGGL(out_kernel, dim3((NCOL+255)/256), dim3(256), 0, stream, ws, psg, out);
}